// Round 3
// baseline (148.054 us; speedup 1.0000x reference)
//
#include <hip/hip_runtime.h>
#include <hip/hip_bf16.h>
#include <math.h>

#define BT 48
#define N 1024
#define F 64
#define CIN 64
#define EM 16
#define LRELU_A 0.2f
#define L2E 1.4426950408889634f

typedef short bf16x8 __attribute__((ext_vector_type(8)));   // 8 bf16 = 4 VGPRs
typedef float f32x4  __attribute__((ext_vector_type(4)));

// exact RTNE float->bf16 bits (k_proj only, off hot path)
__device__ __forceinline__ unsigned short f2bf(float f) {
    unsigned int u = __float_as_uint(f);
    return (unsigned short)((u + 0x7FFFu + ((u >> 16) & 1u)) >> 16);
}

// ------------------------------------------------------------------
// k_proj_misc round 10: 768 blocks (was 900 -> removed 132-block tail).
//  every block: Wh row-block -> WhSw bf16 [bt][nb32][f][slot][j],
//    slot=(q+f)&3 XOR swizzle; + s1/s2 wave reductions.
//  blocks 0..127 additionally: adj bit-pack (256 words each).
//  blocks 128..131 additionally: f1/f2.
// ------------------------------------------------------------------
__global__ __launch_bounds__(256) void k_proj_misc(
    const float* __restrict__ x, const float* __restrict__ W,
    const float* __restrict__ a,
    const int* __restrict__ adj,
    const float* __restrict__ emb1, const float* __restrict__ emb2,
    const float* __restrict__ a2,
    unsigned short* __restrict__ WhSw,
    float* __restrict__ s1, float* __restrict__ s2,
    unsigned int* __restrict__ adjBits,
    float* __restrict__ f1, float* __restrict__ f2)
{
    const int tid = threadIdx.x;
    const int b   = blockIdx.x;

    __shared__ __align__(16) float sx[64 * 64];
    __shared__ __align__(16) float sWT[64 * 68];
    __shared__ __align__(16) unsigned short sT[64 * 80];

    const int bt  = b >> 4;
    const int n0  = (b & 15) * 64;
    const size_t grow = (size_t)bt * N + n0;

    {
        const float4* xv = (const float4*)(x + grow * CIN);
        float4* sxv = (float4*)sx;
        for (int i = tid; i < 64 * CIN / 4; i += 256) sxv[i] = xv[i];
        for (int i = tid; i < CIN * F; i += 256)
            sWT[(i & 63) * 68 + (i >> 6)] = W[i];
    }
    __syncthreads();

    const int f = tid & 63;
    const int w = tid >> 6;
    const float a1 = a[f], a2c = a[F + f];

    float acc[16];
#pragma unroll
    for (int t = 0; t < 16; ++t) acc[t] = 0.f;

    for (int cb = 0; cb < CIN; cb += 4) {
        const float4 wv = *(const float4*)&sWT[f * 68 + cb];
#pragma unroll
        for (int t = 0; t < 16; ++t) {
            const float4 xv = *(const float4*)&sx[(w * 16 + t) * 64 + cb];
            acc[t] = fmaf(xv.x, wv.x, acc[t]);
            acc[t] = fmaf(xv.y, wv.y, acc[t]);
            acc[t] = fmaf(xv.z, wv.z, acc[t]);
            acc[t] = fmaf(xv.w, wv.w, acc[t]);
        }
    }

#pragma unroll
    for (int t = 0; t < 16; ++t) {
        float v1 = acc[t] * a1;
        float v2 = acc[t] * a2c;
#pragma unroll
        for (int off = 32; off >= 1; off >>= 1) {
            v1 += __shfl_xor(v1, off, 64);
            v2 += __shfl_xor(v2, off, 64);
        }
        if (f == 0) {
            s1[grow + w * 16 + t] = v1;
            s2[grow + w * 16 + t] = v2;
        }
        sT[f * 80 + w * 16 + t] = f2bf(acc[t]);
    }
    __syncthreads();

    {
        const int ff = tid >> 2, q = tid & 3;
        const int slot = (q + ff) & 3;
        const int nb0 = (b & 15) * 2;
#pragma unroll
        for (int nbL = 0; nbL < 2; ++nbL) {
            const size_t dst = ((size_t)(bt * 32 + nb0 + nbL) * 64 + ff) * 32 + slot * 8;
            *(uint4*)&WhSw[dst] = *(const uint4*)&sT[ff * 80 + nbL * 32 + q * 8];
        }
    }

    // folded misc work (formerly blocks 768..899) — overlaps other blocks' GEMM
    if (b < 128) {
        const int idx = b * 256 + tid;
        const int r = idx >> 5, w32 = idx & 31;
        const int* p = adj + (size_t)r * N + w32 * 32;
        unsigned int m = 0;
#pragma unroll
        for (int j = 0; j < 32; ++j) m |= (p[j] > 0 ? 1u : 0u) << j;
        adjBits[idx] = m;
    } else if (b < 132) {
        const int n = (b - 128) * 256 + tid;
        float v1 = 0.f, v2 = 0.f;
#pragma unroll
        for (int k = 0; k < EM; ++k) {
            v1 = fmaf(emb1[n * EM + k], a2[k], v1);
            v2 = fmaf(emb2[n * EM + k], a2[EM + k], v2);
        }
        f1[n] = v1; f2[n] = v2;
    }
}

// ------------------------------------------------------------------
// k_attn round 10: identical math to round 9 (factorized rank-1 softmax,
// DMA double-buffer, XOR-swizzled B, single barrier/chunk) BUT the chunk
// pipeline is fully explicit: every call site passes a LITERAL chunk index
// and a LITERAL fragment array (afrA/afrB). Round 9 selected the fragment
// buffer via a runtime pointer ((ch&1)?afrB:afrA) inside a non-unrolled
// loop -> afrA/afrB could not be SROA'd -> 128 B/lane scratch, 8 scratch
// store+load pairs per chunk. That is rule #20 (runtime-indexed register
// arrays go to local memory). Explicit unroll removes the phi entirely.
// ------------------------------------------------------------------
__global__ __launch_bounds__(256, 3) void k_attn(
    const unsigned int* __restrict__ adjBits,
    const unsigned short* __restrict__ WhSw,
    const float* __restrict__ s1, const float* __restrict__ s2,
    const float* __restrict__ f1v, const float* __restrict__ f2v,
    float* __restrict__ out)
{
    __shared__ __align__(16) float sX1[N];                  // 2^c   (scaled domain)
    __shared__ __align__(16) float sX2[N];                  // 2^.2c
    __shared__ __align__(16) unsigned short sB[2][8192];    // 2 x 16 KB
    __shared__ float sWmax[4];

    const int tid  = threadIdx.x;
    const int xcd = blockIdx.x & 7;                         // XCD swizzle: 6 bt/XCD
    const int idx = blockIdx.x >> 3;
    const int bt  = xcd * 6 + (idx >> 4);
    const int i0  = (idx & 15) * 64;
    const int lane = tid & 63;
    const int w    = tid >> 6;
    const int q    = lane >> 4;
    const int m15  = lane & 15;

    // stage X1/X2 and track block max of c (scaled by log2e)
    float cmax = -1e30f;
    for (int j = tid; j < N; j += 256) {
        const float c = (s2[bt * N + j] + f2v[j]) * L2E;
        sX1[j] = exp2f(c);
        sX2[j] = exp2f(LRELU_A * c);
        cmax = fmaxf(cmax, c);
    }
#pragma unroll
    for (int off = 32; off >= 1; off >>= 1) cmax = fmaxf(cmax, __shfl_xor(cmax, off, 64));
    if (lane == 0) sWmax[w] = cmax;
    __syncthreads();
    const float mx = fmaxf(fmaxf(sWmax[0], sWmax[1]), fmaxf(sWmax[2], sWmax[3]));

    const int growq = i0 + w * 16 + m15;
    const float r    = (s1[bt * N + growq] + f1v[growq]) * L2E;   // scaled domain
    const float smx  = r + mx;
    const float mhat = fmaxf(smx, LRELU_A * smx);           // >= every scaled e in row
    const float E1 = exp2f(r - mhat);
    const float E2 = exp2f(LRELU_A * r - mhat);
    const float T  = exp2f(-r);                             // X1 > T <=> c > -r
    float lsum = 0.f;

    const unsigned int* abRow = adjBits + growq * 32;
    const unsigned short* gBbt = WhSw + (size_t)bt * 65536;

    f32x4 acc[4];
#pragma unroll
    for (int ct = 0; ct < 4; ++ct)
#pragma unroll
        for (int e = 0; e < 4; ++e) acc[ct][e] = 0.f;

    auto dma = [&](int ch) {
        const unsigned short* src = gBbt + ch * 8192 + w * 2048 + lane * 8;
        unsigned short* dst = &sB[ch & 1][w * 2048];        // wave-uniform base
#pragma unroll
        for (int it = 0; it < 4; ++it)
            __builtin_amdgcn_global_load_lds(
                (const __attribute__((address_space(1))) unsigned int*)(src + it * 512),
                (__attribute__((address_space(3))) unsigned int*)(dst + it * 512),
                16, 0, 0);
    };
    auto make_afr = [&](int ch, bf16x8* afr) {
        const int k0 = ch * 128;
        const uint4 ab = *(const uint4*)&abRow[ch * 4];
        const unsigned int abw[4] = {ab.x, ab.y, ab.z, ab.w};
#pragma unroll
        for (int ks = 0; ks < 4; ++ks) {
            const int jb = k0 + ks * 32 + q * 8;
            const float4 x1a = *(const float4*)&sX1[jb];
            const float4 x1b = *(const float4*)&sX1[jb + 4];
            const float4 x2a = *(const float4*)&sX2[jb];
            const float4 x2b = *(const float4*)&sX2[jb + 4];
            const float X1[8] = {x1a.x, x1a.y, x1a.z, x1a.w, x1b.x, x1b.y, x1b.z, x1b.w};
            const float X2[8] = {x2a.x, x2a.y, x2a.z, x2a.w, x2b.x, x2b.y, x2b.z, x2b.w};
            const unsigned int mb = (abw[ks] >> (q * 8)) & 0xFFu;
            union { unsigned int u[4]; bf16x8 v; } A;
#pragma unroll
            for (int jp = 0; jp < 4; ++jp) {
                const bool s0 = X1[2 * jp]     > T;
                const bool s1b = X1[2 * jp + 1] > T;
                float p0 = (s0  ? X1[2 * jp]     : X2[2 * jp])     * (s0  ? E1 : E2);
                float p1 = (s1b ? X1[2 * jp + 1] : X2[2 * jp + 1]) * (s1b ? E1 : E2);
                p0 = ((mb >> (2 * jp)) & 1u)     ? p0 : 0.f;
                p1 = ((mb >> (2 * jp + 1)) & 1u) ? p1 : 0.f;
                lsum += p0 + p1;
                A.u[jp] = __builtin_amdgcn_perm(
                    __float_as_uint(p1) + 0x8000u,
                    __float_as_uint(p0) + 0x8000u, 0x07060302u);
            }
            afr[ks] = A.v;
        }
    };
    auto mfma_chunk = [&](int ch, const bf16x8* afr) {
        const char* src = (const char*)sB[ch & 1];
        const int slotoff = ((q + m15) & 3) * 16;           // XOR-swizzled slot
#pragma unroll
        for (int ct = 0; ct < 4; ++ct)
#pragma unroll
            for (int ks = 0; ks < 4; ++ks) {
                const bf16x8 bb = *(const bf16x8*)
                    (src + ks * 4096 + (ct * 16 + m15) * 64 + slotoff);
                acc[ct] = __builtin_amdgcn_mfma_f32_16x16x32_bf16(
                    afr[ks], bb, acc[ct], 0, 0, 0);
            }
    };

    bf16x8 afrA[4], afrB[4];

    // fully explicit 8-chunk pipeline: literal chunk ids, literal frag arrays
    dma(0);
    make_afr(0, afrA);
    __syncthreads();            // vmcnt drain -> sB[0] ready

    dma(1); mfma_chunk(0, afrA); make_afr(1, afrB); __syncthreads();
    dma(2); mfma_chunk(1, afrB); make_afr(2, afrA); __syncthreads();
    dma(3); mfma_chunk(2, afrA); make_afr(3, afrB); __syncthreads();
    dma(4); mfma_chunk(3, afrB); make_afr(4, afrA); __syncthreads();
    dma(5); mfma_chunk(4, afrA); make_afr(5, afrB); __syncthreads();
    dma(6); mfma_chunk(5, afrB); make_afr(6, afrA); __syncthreads();
    dma(7); mfma_chunk(6, afrA); make_afr(7, afrB); __syncthreads();
    mfma_chunk(7, afrB);

    // row denominators: lanes {l, l^16, l^32, l^48} share row m15
    lsum += __shfl_xor(lsum, 16, 64);
    lsum += __shfl_xor(lsum, 32, 64);

    float rinv[4];
#pragma unroll
    for (int reg = 0; reg < 4; ++reg)
        rinv[reg] = 1.f / __shfl(lsum, q * 4 + reg, 64);

#pragma unroll
    for (int ct = 0; ct < 4; ++ct) {
#pragma unroll
        for (int reg = 0; reg < 4; ++reg) {
            float h = acc[ct][reg] * rinv[reg];
            h = (h > 0.f) ? h : (__expf(h) - 1.f);          // ELU
            out[(size_t)(bt * N + i0 + w * 16 + q * 4 + reg) * F + ct * 16 + m15] = h;
        }
    }
}

// ------------------------------------------------------------------
extern "C" void kernel_launch(void* const* d_in, const int* in_sizes, int n_in,
                              void* d_out, int out_size, void* d_ws, size_t ws_size,
                              hipStream_t stream)
{
    const float* x    = (const float*)d_in[0];
    const int*   adj  = (const int*)  d_in[1];
    const float* emb1 = (const float*)d_in[2];
    const float* emb2 = (const float*)d_in[3];
    const float* W    = (const float*)d_in[4];
    const float* a    = (const float*)d_in[5];
    const float* a2   = (const float*)d_in[6];
    float* out = (float*)d_out;

    unsigned short* WhSw = (unsigned short*)d_ws;             // 6.29 MB
    float* s1 = (float*)(WhSw + (size_t)BT * 65536);
    float* s2 = s1 + BT * N;
    float* f1 = s2 + BT * N;
    float* f2 = f1 + N;
    unsigned int* adjBits = (unsigned int*)(f2 + N);          // 128 KB

    hipLaunchKernelGGL(k_proj_misc, dim3(768), dim3(256), 0, stream,
                       x, W, a, adj, emb1, emb2, a2, WhSw, s1, s2, adjBits, f1, f2);
    hipLaunchKernelGGL(k_attn, dim3(BT * 16), dim3(256), 0, stream,
                       adjBits, WhSw, s1, s2, f1, f2, out);
}

// Round 4
// 118.343 us; speedup vs baseline: 1.2511x; 1.2511x over previous
//
#include <hip/hip_runtime.h>
#include <hip/hip_bf16.h>
#include <math.h>

#define BT 48
#define N 1024
#define F 64
#define CIN 64
#define EM 16
#define LRELU_A 0.2f
#define L2E 1.4426950408889634f

typedef short bf16x8 __attribute__((ext_vector_type(8)));   // 8 bf16 = 4 VGPRs
typedef float f32x4  __attribute__((ext_vector_type(4)));
typedef unsigned int u32x4 __attribute__((ext_vector_type(4)));

// exact RTNE float->bf16 bits (k_proj only, off hot path)
__device__ __forceinline__ unsigned short f2bf(float f) {
    unsigned int u = __float_as_uint(f);
    return (unsigned short)((u + 0x7FFFu + ((u >> 16) & 1u)) >> 16);
}

// ------------------------------------------------------------------
// k_proj_misc (unchanged from round 10): 768 blocks.
//  every block: Wh row-block -> WhSw bf16 [bt][nb32][f][slot][j],
//    slot=(q+f)&3 XOR swizzle; + s1/s2 wave reductions.
//  blocks 0..127 additionally: adj bit-pack. blocks 128..131: f1/f2.
// ------------------------------------------------------------------
__global__ __launch_bounds__(256) void k_proj_misc(
    const float* __restrict__ x, const float* __restrict__ W,
    const float* __restrict__ a,
    const int* __restrict__ adj,
    const float* __restrict__ emb1, const float* __restrict__ emb2,
    const float* __restrict__ a2,
    unsigned short* __restrict__ WhSw,
    float* __restrict__ s1, float* __restrict__ s2,
    unsigned int* __restrict__ adjBits,
    float* __restrict__ f1, float* __restrict__ f2)
{
    const int tid = threadIdx.x;
    const int b   = blockIdx.x;

    __shared__ __align__(16) float sx[64 * 64];
    __shared__ __align__(16) float sWT[64 * 68];
    __shared__ __align__(16) unsigned short sT[64 * 80];

    const int bt  = b >> 4;
    const int n0  = (b & 15) * 64;
    const size_t grow = (size_t)bt * N + n0;

    {
        const float4* xv = (const float4*)(x + grow * CIN);
        float4* sxv = (float4*)sx;
        for (int i = tid; i < 64 * CIN / 4; i += 256) sxv[i] = xv[i];
        for (int i = tid; i < CIN * F; i += 256)
            sWT[(i & 63) * 68 + (i >> 6)] = W[i];
    }
    __syncthreads();

    const int f = tid & 63;
    const int w = tid >> 6;
    const float a1 = a[f], a2c = a[F + f];

    float acc[16];
#pragma unroll
    for (int t = 0; t < 16; ++t) acc[t] = 0.f;

    for (int cb = 0; cb < CIN; cb += 4) {
        const float4 wv = *(const float4*)&sWT[f * 68 + cb];
#pragma unroll
        for (int t = 0; t < 16; ++t) {
            const float4 xv = *(const float4*)&sx[(w * 16 + t) * 64 + cb];
            acc[t] = fmaf(xv.x, wv.x, acc[t]);
            acc[t] = fmaf(xv.y, wv.y, acc[t]);
            acc[t] = fmaf(xv.z, wv.z, acc[t]);
            acc[t] = fmaf(xv.w, wv.w, acc[t]);
        }
    }

#pragma unroll
    for (int t = 0; t < 16; ++t) {
        float v1 = acc[t] * a1;
        float v2 = acc[t] * a2c;
#pragma unroll
        for (int off = 32; off >= 1; off >>= 1) {
            v1 += __shfl_xor(v1, off, 64);
            v2 += __shfl_xor(v2, off, 64);
        }
        if (f == 0) {
            s1[grow + w * 16 + t] = v1;
            s2[grow + w * 16 + t] = v2;
        }
        sT[f * 80 + w * 16 + t] = f2bf(acc[t]);
    }
    __syncthreads();

    {
        const int ff = tid >> 2, q = tid & 3;
        const int slot = (q + ff) & 3;
        const int nb0 = (b & 15) * 2;
#pragma unroll
        for (int nbL = 0; nbL < 2; ++nbL) {
            const size_t dst = ((size_t)(bt * 32 + nb0 + nbL) * 64 + ff) * 32 + slot * 8;
            *(uint4*)&WhSw[dst] = *(const uint4*)&sT[ff * 80 + nbL * 32 + q * 8];
        }
    }

    if (b < 128) {
        const int idx = b * 256 + tid;
        const int r = idx >> 5, w32 = idx & 31;
        const int* p = adj + (size_t)r * N + w32 * 32;
        unsigned int m = 0;
#pragma unroll
        for (int j = 0; j < 32; ++j) m |= (p[j] > 0 ? 1u : 0u) << j;
        adjBits[idx] = m;
    } else if (b < 132) {
        const int n = (b - 128) * 256 + tid;
        float v1 = 0.f, v2 = 0.f;
#pragma unroll
        for (int k = 0; k < EM; ++k) {
            v1 = fmaf(emb1[n * EM + k], a2[k], v1);
            v2 = fmaf(emb2[n * EM + k], a2[EM + k], v2);
        }
        f1[n] = v1; f2[n] = v2;
    }
}

// ------------------------------------------------------------------
// k_attn round 11: SCRATCH ELIMINATION. Round-10 counters showed
// WRITE_SIZE=129MiB (10x the 12.6MB out tensor), VGPR=84 (<<168 cap),
// MfmaUtil=2.4% -> fragment arrays lived in scratch: lambda pointer
// params (bf16x8* afr) defeat SROA even with literal indices.
// Fix: NO arrays / NO pointer-passing / NO unions in the hot path.
// Fragments = 8 named bf16x8; accs = 4 named f32x4; bf16-pack via
// __builtin_bit_cast of a named u32x4. All code via macros (textual
// inline). Math identical to round 9/10 (factorized rank-1 softmax).
// ------------------------------------------------------------------

// pack two masked probs into one u32 (two bf16): p0 -> low16, p1 -> high16
#define PAIR(x1e, x1o, x2e, x2o, bit, dest) do {                           \
    const bool s0_ = (x1e) > T;                                            \
    const bool s1_ = (x1o) > T;                                            \
    float p0_ = (s0_ ? (x1e) : (x2e)) * (s0_ ? E1 : E2);                   \
    float p1_ = (s1_ ? (x1o) : (x2o)) * (s1_ ? E1 : E2);                   \
    p0_ = ((mb_ >> (bit)) & 1u) ? p0_ : 0.f;                               \
    p1_ = ((mb_ >> ((bit) + 1)) & 1u) ? p1_ : 0.f;                         \
    lsum += p0_ + p1_;                                                     \
    dest = __builtin_amdgcn_perm(__float_as_uint(p1_) + 0x8000u,           \
                                 __float_as_uint(p0_) + 0x8000u,           \
                                 0x07060302u);                             \
} while (0)

// build one A-fragment (8 probs for k-slice ks of chunk ch) into named var
#define MAKE_ONE(ch, ks, Avar, abword) do {                                \
    const int jb_ = (ch) * 128 + (ks) * 32 + q * 8;                        \
    const float4 x1a_ = *(const float4*)&sX1[jb_];                         \
    const float4 x1b_ = *(const float4*)&sX1[jb_ + 4];                     \
    const float4 x2a_ = *(const float4*)&sX2[jb_];                         \
    const float4 x2b_ = *(const float4*)&sX2[jb_ + 4];                     \
    const unsigned int mb_ = ((abword) >> (q * 8)) & 0xFFu;                \
    unsigned int u0_, u1_, u2_, u3_;                                       \
    PAIR(x1a_.x, x1a_.y, x2a_.x, x2a_.y, 0, u0_);                          \
    PAIR(x1a_.z, x1a_.w, x2a_.z, x2a_.w, 2, u1_);                          \
    PAIR(x1b_.x, x1b_.y, x2b_.x, x2b_.y, 4, u2_);                          \
    PAIR(x1b_.z, x1b_.w, x2b_.z, x2b_.w, 6, u3_);                          \
    u32x4 av_; av_.x = u0_; av_.y = u1_; av_.z = u2_; av_.w = u3_;         \
    Avar = __builtin_bit_cast(bf16x8, av_);                                \
} while (0)

#define MAKE_AFR(ch, A0, A1, A2, A3) do {                                  \
    const uint4 ab_ = *(const uint4*)&abRow[(ch) * 4];                     \
    MAKE_ONE(ch, 0, A0, ab_.x);                                            \
    MAKE_ONE(ch, 1, A1, ab_.y);                                            \
    MAKE_ONE(ch, 2, A2, ab_.z);                                            \
    MAKE_ONE(ch, 3, A3, ab_.w);                                            \
} while (0)

#define MFMA_KS(ct, ks, Af) do {                                           \
    const bf16x8 bb_ = *(const bf16x8*)(src_ + (ks) * 4096 +               \
                        ((ct) * 16 + m15) * 64 + slotoff);                 \
    acc##ct = __builtin_amdgcn_mfma_f32_16x16x32_bf16(Af, bb_, acc##ct,    \
                                                      0, 0, 0);            \
} while (0)

#define MFMA_CT(ct, A0, A1, A2, A3) do {                                   \
    MFMA_KS(ct, 0, A0); MFMA_KS(ct, 1, A1);                                \
    MFMA_KS(ct, 2, A2); MFMA_KS(ct, 3, A3);                                \
} while (0)

#define MFMA_CHUNK(ch, A0, A1, A2, A3) do {                                \
    const char* src_ = (const char*)sB[(ch) & 1];                          \
    MFMA_CT(0, A0, A1, A2, A3); MFMA_CT(1, A0, A1, A2, A3);                \
    MFMA_CT(2, A0, A1, A2, A3); MFMA_CT(3, A0, A1, A2, A3);                \
} while (0)

#define DMA(ch) do {                                                       \
    const unsigned short* dsrc_ = gBbt + (ch) * 8192 + w * 2048 + lane * 8;\
    unsigned short* ddst_ = &sB[(ch) & 1][w * 2048];                       \
    __builtin_amdgcn_global_load_lds(                                      \
        (const __attribute__((address_space(1))) unsigned int*)(dsrc_),    \
        (__attribute__((address_space(3))) unsigned int*)(ddst_), 16, 0, 0);\
    __builtin_amdgcn_global_load_lds(                                      \
        (const __attribute__((address_space(1))) unsigned int*)(dsrc_+512),\
        (__attribute__((address_space(3))) unsigned int*)(ddst_+512), 16, 0, 0);\
    __builtin_amdgcn_global_load_lds(                                      \
        (const __attribute__((address_space(1))) unsigned int*)(dsrc_+1024),\
        (__attribute__((address_space(3))) unsigned int*)(ddst_+1024), 16, 0, 0);\
    __builtin_amdgcn_global_load_lds(                                      \
        (const __attribute__((address_space(1))) unsigned int*)(dsrc_+1536),\
        (__attribute__((address_space(3))) unsigned int*)(ddst_+1536), 16, 0, 0);\
} while (0)

#define EPI(ct, accv) do {                                                 \
    float h0_ = accv.x * rinv0, h1_ = accv.y * rinv1,                      \
          h2_ = accv.z * rinv2, h3_ = accv.w * rinv3;                      \
    h0_ = (h0_ > 0.f) ? h0_ : (__expf(h0_) - 1.f);                         \
    h1_ = (h1_ > 0.f) ? h1_ : (__expf(h1_) - 1.f);                         \
    h2_ = (h2_ > 0.f) ? h2_ : (__expf(h2_) - 1.f);                         \
    h3_ = (h3_ > 0.f) ? h3_ : (__expf(h3_) - 1.f);                         \
    float* op_ = out + (size_t)(bt * N + i0 + w * 16 + q * 4) * F          \
                 + (ct) * 16 + m15;                                        \
    op_[0 * F] = h0_; op_[1 * F] = h1_; op_[2 * F] = h2_; op_[3 * F] = h3_;\
} while (0)

__global__ __launch_bounds__(256, 3) void k_attn(
    const unsigned int* __restrict__ adjBits,
    const unsigned short* __restrict__ WhSw,
    const float* __restrict__ s1, const float* __restrict__ s2,
    const float* __restrict__ f1v, const float* __restrict__ f2v,
    float* __restrict__ out)
{
    __shared__ __align__(16) float sX1[N];                  // 2^c   (scaled domain)
    __shared__ __align__(16) float sX2[N];                  // 2^.2c
    __shared__ __align__(16) unsigned short sB[2][8192];    // 2 x 16 KB
    __shared__ float sWmax[4];

    const int tid  = threadIdx.x;
    const int xcd = blockIdx.x & 7;                         // XCD swizzle: 6 bt/XCD
    const int idx = blockIdx.x >> 3;
    const int bt  = xcd * 6 + (idx >> 4);
    const int i0  = (idx & 15) * 64;
    const int lane = tid & 63;
    const int w    = tid >> 6;
    const int q    = lane >> 4;
    const int m15  = lane & 15;

    // stage X1/X2 and track block max of c (scaled by log2e)
    float cmax = -1e30f;
    for (int j = tid; j < N; j += 256) {
        const float c = (s2[bt * N + j] + f2v[j]) * L2E;
        sX1[j] = exp2f(c);
        sX2[j] = exp2f(LRELU_A * c);
        cmax = fmaxf(cmax, c);
    }
#pragma unroll
    for (int off = 32; off >= 1; off >>= 1) cmax = fmaxf(cmax, __shfl_xor(cmax, off, 64));
    if (lane == 0) sWmax[w] = cmax;
    __syncthreads();
    const float mx = fmaxf(fmaxf(sWmax[0], sWmax[1]), fmaxf(sWmax[2], sWmax[3]));

    const int growq = i0 + w * 16 + m15;
    const float r    = (s1[bt * N + growq] + f1v[growq]) * L2E;   // scaled domain
    const float smx  = r + mx;
    const float mhat = fmaxf(smx, LRELU_A * smx);           // >= every scaled e in row
    const float E1 = exp2f(r - mhat);
    const float E2 = exp2f(LRELU_A * r - mhat);
    const float T  = exp2f(-r);                             // X1 > T <=> c > -r
    float lsum = 0.f;

    const unsigned int* abRow = adjBits + growq * 32;
    const unsigned short* gBbt = WhSw + (size_t)bt * 65536;
    const int slotoff = ((q + m15) & 3) * 16;               // XOR-swizzled slot

    f32x4 acc0 = 0.f, acc1 = 0.f, acc2 = 0.f, acc3 = 0.f;
    bf16x8 fA0, fA1, fA2, fA3, fB0, fB1, fB2, fB3;

    // fully explicit 8-chunk pipeline, all-named state
    DMA(0);
    MAKE_AFR(0, fA0, fA1, fA2, fA3);
    __syncthreads();            // vmcnt drain -> sB[0] ready

    DMA(1); MFMA_CHUNK(0, fA0, fA1, fA2, fA3); MAKE_AFR(1, fB0, fB1, fB2, fB3); __syncthreads();
    DMA(2); MFMA_CHUNK(1, fB0, fB1, fB2, fB3); MAKE_AFR(2, fA0, fA1, fA2, fA3); __syncthreads();
    DMA(3); MFMA_CHUNK(2, fA0, fA1, fA2, fA3); MAKE_AFR(3, fB0, fB1, fB2, fB3); __syncthreads();
    DMA(4); MFMA_CHUNK(3, fB0, fB1, fB2, fB3); MAKE_AFR(4, fA0, fA1, fA2, fA3); __syncthreads();
    DMA(5); MFMA_CHUNK(4, fA0, fA1, fA2, fA3); MAKE_AFR(5, fB0, fB1, fB2, fB3); __syncthreads();
    DMA(6); MFMA_CHUNK(5, fB0, fB1, fB2, fB3); MAKE_AFR(6, fA0, fA1, fA2, fA3); __syncthreads();
    DMA(7); MFMA_CHUNK(6, fA0, fA1, fA2, fA3); MAKE_AFR(7, fB0, fB1, fB2, fB3); __syncthreads();
    MFMA_CHUNK(7, fB0, fB1, fB2, fB3);

    // row denominators: lanes {l, l^16, l^32, l^48} share row m15
    lsum += __shfl_xor(lsum, 16, 64);
    lsum += __shfl_xor(lsum, 32, 64);

    const float rinv0 = 1.f / __shfl(lsum, q * 4 + 0, 64);
    const float rinv1 = 1.f / __shfl(lsum, q * 4 + 1, 64);
    const float rinv2 = 1.f / __shfl(lsum, q * 4 + 2, 64);
    const float rinv3 = 1.f / __shfl(lsum, q * 4 + 3, 64);

    EPI(0, acc0); EPI(1, acc1); EPI(2, acc2); EPI(3, acc3);
}

// ------------------------------------------------------------------
extern "C" void kernel_launch(void* const* d_in, const int* in_sizes, int n_in,
                              void* d_out, int out_size, void* d_ws, size_t ws_size,
                              hipStream_t stream)
{
    const float* x    = (const float*)d_in[0];
    const int*   adj  = (const int*)  d_in[1];
    const float* emb1 = (const float*)d_in[2];
    const float* emb2 = (const float*)d_in[3];
    const float* W    = (const float*)d_in[4];
    const float* a    = (const float*)d_in[5];
    const float* a2   = (const float*)d_in[6];
    float* out = (float*)d_out;

    unsigned short* WhSw = (unsigned short*)d_ws;             // 6.29 MB
    float* s1 = (float*)(WhSw + (size_t)BT * 65536);
    float* s2 = s1 + BT * N;
    float* f1 = s2 + BT * N;
    float* f2 = f1 + N;
    unsigned int* adjBits = (unsigned int*)(f2 + N);          // 128 KB

    hipLaunchKernelGGL(k_proj_misc, dim3(768), dim3(256), 0, stream,
                       x, W, a, adj, emb1, emb2, a2, WhSw, s1, s2, adjBits, f1, f2);
    hipLaunchKernelGGL(k_attn, dim3(BT * 16), dim3(256), 0, stream,
                       adjBits, WhSw, s1, s2, f1, f2, out);
}